// Round 14
// baseline (253.629 us; speedup 1.0000x reference)
//
#include <hip/hip_runtime.h>
#include <math.h>

#define LL 128                  // sequence length
#define LP 132                  // padded row stride: group-base stride 133==5 (mod 32)
#define TCR 160                 // tC rows incl. guard (tail strided reads reach row 158)
#define TC_SZ (TCR * LP)        // 21120 floats
#define TI_SZ (LL * LP + 48)    // 16944 floats
#define NT 1024
#define NW 16

#define LOG2E 1.4426950408889634f
#define LN2   0.6931471805599453f

// DPP quad reductions + ds_swizzle xor exchanges (proven r9/r13).
template <int CTRL>
__device__ __forceinline__ float dppq(float v) {
  return __int_as_float(__builtin_amdgcn_update_dpp(
      0, __float_as_int(v), CTRL, 0xF, 0xF, true));
}
template <int MASK>
__device__ __forceinline__ float swz(float v) {
  return __int_as_float(__builtin_amdgcn_ds_swizzle(
      __float_as_int(v), (MASK << 10) | 0x1F));
}
__device__ __forceinline__ float g8max(float v) {
  v = fmaxf(v, dppq<0xB1>(v));
  v = fmaxf(v, dppq<0x4E>(v));
  v = fmaxf(v, dppq<0x141>(v));   // row_half_mirror: xor4 within 8 lanes
  return v;
}
__device__ __forceinline__ float g8sum(float v) {
  v += dppq<0xB1>(v);
  v += dppq<0x4E>(v);
  v += dppq<0x141>(v);
  return v;
}
template <int G>
__device__ __forceinline__ float gmaxr(float v) {
  v = fmaxf(v, dppq<0xB1>(v));
  v = fmaxf(v, dppq<0x4E>(v));
  if constexpr (G >= 8)  v = fmaxf(v, swz<4>(v));
  if constexpr (G >= 16) v = fmaxf(v, swz<8>(v));
  if constexpr (G >= 32) v = fmaxf(v, swz<16>(v));
  return v;
}
template <int G>
__device__ __forceinline__ float gsumr(float v) {
  v += dppq<0xB1>(v);
  v += dppq<0x4E>(v);
  if constexpr (G >= 8)  v += swz<4>(v);
  if constexpr (G >= 16) v += swz<8>(v);
  if constexpr (G >= 32) v += swz<16>(v);
  return v;
}

// -------- w<=64: 8-lane group per i, register streams (r13, proven) --------
template <int K>
__device__ __forceinline__ void fusedPhase(
    float* __restrict__ tC, float* __restrict__ tI, const float* __restrict__ S,
    const int ii, const int w, const int lg, const bool writer,
    const bool rootBad, float (&paR)[9], float (&a1R)[9], float (&c1R)[8]) {
  const float sUp = S[ii * LL + ii + w];
  const float sLo = S[(ii + w) * LL + ii];
  const float* pb = tC + (ii + w) * LP + ii + 1 + lg;   // [8k]
  const float* a2 = tI + (ii + w) * LP + ii + lg;       // [8k]
  const float* c2 = tC + (ii + 1 + lg) * LP + ii + w;   // [8k*LP]

  float vb[K], va[K];
#pragma unroll
  for (int k = 0; k < K; ++k) vb[k] = pb[8 * k];
#pragma unroll
  for (int k = 0; k < K; ++k) va[k] = a2[8 * k];
  __builtin_amdgcn_sched_barrier(0);

  // A: il = lse_j[ sc[ii][ii+j] + sc[ii+w][ii+j+1] ]
  float mA0 = -INFINITY, mA1 = -INFINITY;
#pragma unroll
  for (int k = 0; k < K; ++k) {
    float x = paR[k] + vb[k];
    if (k & 1) mA1 = fmaxf(mA1, x); else mA0 = fmaxf(mA0, x);
  }
  const float msA = fmaxf(g8max(fmaxf(mA0, mA1)), -1e37f);
  const float nA = -msA * LOG2E;
  float sA0 = 0.f, sA1 = 0.f;
#pragma unroll
  for (int k = 0; k < K; ++k) {
    float e = __builtin_amdgcn_exp2f(__builtin_fmaf(paR[k] + vb[k], LOG2E, nA));
    if (k & 1) sA1 += e; else sA0 += e;
  }
  const float il = __builtin_amdgcn_logf(g8sum(sA0 + sA1)) * LN2 + msA;

  // L bulk: lse_j[ sc[ii+j][ii] + si[ii+w][ii+j] ], j in [1,w)
  float mL0 = -INFINITY, mL1 = -INFINITY;
#pragma unroll
  for (int k = 0; k < K; ++k) {
    float x = a1R[k] + va[k];
    if (k & 1) mL1 = fmaxf(mL1, x); else mL0 = fmaxf(mL0, x);
  }
  const float mL = g8max(fmaxf(mL0, mL1));
  const float msL = fmaxf(mL, -1e37f);
  const float nL = -msL * LOG2E;
  float sL0 = 0.f, sL1 = 0.f;
#pragma unroll
  for (int k = 0; k < K; ++k) {
    float e = __builtin_amdgcn_exp2f(__builtin_fmaf(a1R[k] + va[k], LOG2E, nL));
    if (k & 1) sL1 += e; else sL0 += e;
  }
  const float SL = g8sum(sL0 + sL1);

  float vc[K];
#pragma unroll
  for (int k = 0; k < K; ++k) vc[k] = c2[8 * k * LP];
  __builtin_amdgcn_sched_barrier(0);

  // R bulk: lse_d[ si[ii][ii+d] + sc[ii+d][ii+w] ], d in [1,w-1]
  float mR0 = -INFINITY, mR1 = -INFINITY;
#pragma unroll
  for (int k = 0; k < K; ++k) {
    float x = c1R[k] + vc[k];
    if (k & 1) mR1 = fmaxf(mR1, x); else mR0 = fmaxf(mR0, x);
  }
  const float mR = g8max(fmaxf(mR0, mR1));
  const float msR = fmaxf(mR, -1e37f);
  const float nR = -msR * LOG2E;
  float sR0 = 0.f, sR1 = 0.f;
#pragma unroll
  for (int k = 0; k < K; ++k) {
    float e = __builtin_amdgcn_exp2f(__builtin_fmaf(c1R[k] + vc[k], LOG2E, nR));
    if (k & 1) sR1 += e; else sR0 += e;
  }
  const float SR = g8sum(sR0 + sR1);

  const float t0 = il + sUp;
  const float tW = il + sLo;
  const float msfL = fmaxf(fmaxf(mL, t0), -1e37f);
  const float SLf = SL * __builtin_amdgcn_exp2f((msL - msfL) * LOG2E)
                  + __builtin_amdgcn_exp2f((t0 - msfL) * LOG2E);
  const float clv = __builtin_amdgcn_logf(SLf) * LN2 + msfL;
  const float msfR = fmaxf(fmaxf(mR, tW), -1e37f);
  const float SRf = SR * __builtin_amdgcn_exp2f((msR - msfR) * LOG2E)
                  + __builtin_amdgcn_exp2f((tW - msfR) * LOG2E);
  float crv = __builtin_amdgcn_logf(SRf) * LN2 + msfR;
  if (rootBad) crv = -INFINITY;

  if (writer) {
    tI[(ii + w) * LP + ii] = t0;
    tI[ii * LP + (ii + w)] = tW;
    tC[(ii + w) * LP + ii] = clv;
    tC[ii * LP + (ii + w)] = crv;
  }

  // register appends (static slots; streams only consumed through w=64)
  const int wm7 = w & 7;
  const bool lnw = (lg == wm7) && (wm7 != 0);
  paR[K - 1] = lnw ? crv : paR[K - 1];
  a1R[K - 1] = lnw ? clv : a1R[K - 1];
  {
    const bool z = (lg == 0) && (wm7 == 0);
    paR[K] = z ? crv : paR[K];     // K<=8, arrays sized 9
    a1R[K] = z ? clv : a1R[K];
  }
  const bool ln1 = (lg == ((w - 1) & 7));
  c1R[K - 1] = ln1 ? tW : c1R[K - 1];
}

// -------- w>64: G lanes per i, all 6 streams from LDS (r9 widePhase) ------
template <int G, int KG>
__device__ __forceinline__ void widePhase(
    float* __restrict__ tC, float* __restrict__ tI, const float* __restrict__ S,
    const int ii, const int w, const int jgg, const bool writer,
    const bool rootBad) {
  const float sUp = S[ii * LL + ii + w];
  const float sLo = S[(ii + w) * LL + ii];
  const float* pa = tC + ii * LP + ii + jgg;
  const float* pb = tC + (ii + w) * LP + ii + 1 + jgg;
  const float* a1 = tC + (ii + jgg) * LP + ii;
  const float* a2 = tI + (ii + w) * LP + ii + jgg;
  const float* c1 = tI + ii * LP + ii + 1 + jgg;
  const float* c2 = tC + (ii + 1 + jgg) * LP + ii + w;

  float xa[KG], xl[KG], xr[KG];
  const unsigned uw = (unsigned)w, uw1 = (unsigned)(w - 1);
#pragma unroll
  for (int k = 0; k < KG; ++k) {
    float va_ = pa[G * k] + pb[G * k];
    float vl_ = a1[G * k * LP] + a2[G * k];
    float vr_ = c1[G * k] + c2[G * k * LP];
    const unsigned j = (unsigned)(jgg + G * k);
    xa[k] = (j < uw) ? va_ : -INFINITY;        // A: j in [0,w)
    xl[k] = (j - 1u < uw1) ? vl_ : -INFINITY;  // L bulk: j in [1,w)
    xr[k] = (j < uw1) ? vr_ : -INFINITY;       // R bulk: j in [0,w-1)
  }

  float mA0 = -INFINITY, mA1 = -INFINITY;
#pragma unroll
  for (int k = 0; k < KG; ++k) {
    if (k & 1) mA1 = fmaxf(mA1, xa[k]); else mA0 = fmaxf(mA0, xa[k]);
  }
  const float msA = fmaxf(gmaxr<G>(fmaxf(mA0, mA1)), -1e37f);
  const float nA = -msA * LOG2E;
  float sA0 = 0.f, sA1 = 0.f;
#pragma unroll
  for (int k = 0; k < KG; ++k) {
    float e = __builtin_amdgcn_exp2f(__builtin_fmaf(xa[k], LOG2E, nA));
    if (k & 1) sA1 += e; else sA0 += e;
  }
  const float il = __builtin_amdgcn_logf(gsumr<G>(sA0 + sA1)) * LN2 + msA;

  float mL0 = -INFINITY, mL1 = -INFINITY;
#pragma unroll
  for (int k = 0; k < KG; ++k) {
    if (k & 1) mL1 = fmaxf(mL1, xl[k]); else mL0 = fmaxf(mL0, xl[k]);
  }
  const float mL = gmaxr<G>(fmaxf(mL0, mL1));
  const float msL = fmaxf(mL, -1e37f);
  const float nL = -msL * LOG2E;
  float sL0 = 0.f, sL1 = 0.f;
#pragma unroll
  for (int k = 0; k < KG; ++k) {
    float e = __builtin_amdgcn_exp2f(__builtin_fmaf(xl[k], LOG2E, nL));
    if (k & 1) sL1 += e; else sL0 += e;
  }
  const float SL = gsumr<G>(sL0 + sL1);

  float mR0 = -INFINITY, mR1 = -INFINITY;
#pragma unroll
  for (int k = 0; k < KG; ++k) {
    if (k & 1) mR1 = fmaxf(mR1, xr[k]); else mR0 = fmaxf(mR0, xr[k]);
  }
  const float mR = gmaxr<G>(fmaxf(mR0, mR1));
  const float msR = fmaxf(mR, -1e37f);
  const float nR = -msR * LOG2E;
  float sR0 = 0.f, sR1 = 0.f;
#pragma unroll
  for (int k = 0; k < KG; ++k) {
    float e = __builtin_amdgcn_exp2f(__builtin_fmaf(xr[k], LOG2E, nR));
    if (k & 1) sR1 += e; else sR0 += e;
  }
  const float SR = gsumr<G>(sR0 + sR1);

  const float t0 = il + sUp;
  const float tW = il + sLo;
  const float msfL = fmaxf(fmaxf(mL, t0), -1e37f);
  const float SLf = SL * __builtin_amdgcn_exp2f((msL - msfL) * LOG2E)
                  + __builtin_amdgcn_exp2f((t0 - msfL) * LOG2E);
  const float clv = __builtin_amdgcn_logf(SLf) * LN2 + msfL;
  const float msfR = fmaxf(fmaxf(mR, tW), -1e37f);
  const float SRf = SR * __builtin_amdgcn_exp2f((msR - msfR) * LOG2E)
                  + __builtin_amdgcn_exp2f((tW - msfR) * LOG2E);
  float crv = __builtin_amdgcn_logf(SRf) * LN2 + msfR;
  if (rootBad) crv = -INFINITY;

  if (writer) {
    tI[(ii + w) * LP + ii] = t0;
    tI[ii * LP + (ii + w)] = tW;
    tC[(ii + w) * LP + ii] = clv;
    tC[ii * LP + (ii + w)] = crv;
  }
}

__global__ __launch_bounds__(NT)
__attribute__((amdgpu_waves_per_eu(4, 4)))
void crf_inside(
    const float* __restrict__ scores, const int* __restrict__ mask,
    const int* __restrict__ target, float* __restrict__ acc) {
  extern __shared__ float lds[];
  float* tC = lds;          // complete spans (160 rows incl. guard)
  float* tI = lds + TC_SZ;  // incomplete spans
  const int b = blockIdx.x;
  const int t = threadIdx.x;
  const int lane = t & 63;
  const int wv = t >> 6;
  const int g = t >> 3;     // 8-lane group index (0..127)
  const int lg = t & 7;
  const float* S = scores + (size_t)b * LL * LL;

  __shared__ float gred[NW];
  __shared__ int lred[NW];
  __shared__ float s_gold;
  __shared__ int s_len;

  // ---- lens + masked gold-score reduction ----
  int mv = 0; float gv = 0.f;
  if (t < LL) {
    mv = mask[b * LL + t] ? 1 : 0;
    if (mv) gv = S[t * LL + target[b * LL + t]];
  }
  int lm = mv; float lg_ = gv;
#pragma unroll
  for (int o = 32; o > 0; o >>= 1) {
    lm += __shfl_xor(lm, o, 64);
    lg_ += __shfl_xor(lg_, o, 64);
  }
  if (lane == 0) { lred[wv] = lm; gred[wv] = lg_; }

  // ---- init LDS (incl. guards) to -inf; diag of s_c = 0 ----
  for (int idx = t; idx < TC_SZ + TI_SZ; idx += NT) lds[idx] = -INFINITY;
  __syncthreads();
  if (t < LL) tC[t * LP + t] = 0.f;
  if (t == 0) {
    int l = 0; float gg = 0.f;
    for (int k = 0; k < NW; ++k) { l += lred[k]; gg += gred[k]; }
    s_len = l; s_gold = gg;
  }
  __syncthreads();
  const int len = s_len;

  // ---- register streams (w<=64 only): -inf; paR[0]=diag 0 on lg==0 ----
  float paR[9], a1R[9], c1R[8];
#pragma unroll
  for (int k = 0; k < 9; ++k) { paR[k] = -INFINITY; a1R[k] = -INFINITY; }
#pragma unroll
  for (int k = 0; k < 8; ++k) c1R[k] = -INFINITY;
  if (lg == 0) paR[0] = 0.f;

  // ---- regime 1: w = 1..64, G=8 with register streams ----
  for (int w = 1; w <= 64; ++w) {
    const int ni = LL - w;
    const bool waveAct = (wv << 3) < ni;
    const int ii = min(g, ni - 1);
    const bool writer = (lg == 0) & (g < ni);
    const bool rootBad = (ii == 0) && (w != len);
    const int K = (w + 7) >> 3;
    if (waveAct) {
      switch (K) {
#define CASE_K(KK) case KK: fusedPhase<KK>(tC, tI, S, ii, w, lg, writer, rootBad, paR, a1R, c1R); break;
        CASE_K(1) CASE_K(2) CASE_K(3) CASE_K(4)
        CASE_K(5) CASE_K(6) CASE_K(7) CASE_K(8)
#undef CASE_K
      }
    }
    __syncthreads();
  }

  // ---- regime 2: w = 65..96, G=16 (64 groups >= ni, all waves active) ----
  for (int w = 65; w <= 96; ++w) {
    const int ni = LL - w;
    const int gi = t >> 4, jgg = t & 15;
    if ((wv << 2) < ni) {
      const int ii = min(gi, ni - 1);
      const bool writer = (jgg == 0) & (gi < ni);
      const bool rootBad = (ii == 0) && (w != len);
      widePhase<16, 6>(tC, tI, S, ii, w, jgg, writer, rootBad);
    }
    __syncthreads();
  }

  // ---- regime 3: w = 97..127, G=32 (32 groups >= ni) ----
  for (int w = 97; w < LL; ++w) {
    const int ni = LL - w;
    const int gi = t >> 5, jgg = t & 31;
    if ((wv << 1) < ni) {
      const int ii = min(gi, ni - 1);
      const bool writer = (jgg == 0) & (gi < ni);
      const bool rootBad = (ii == 0) && (w != len);
      widePhase<32, 4>(tC, tI, S, ii, w, jgg, writer, rootBad);
    }
    __syncthreads();
  }

  // ---- per-batch contribution ----
  if (t == 0) {
    float logZ = tC[len];  // sc[0][len]
    atomicAdd(&acc[0], logZ - s_gold);
    atomicAdd(&acc[1], (float)len);
  }
}

__global__ void zero_acc(float* acc) {
  acc[0] = 0.f;
  acc[1] = 0.f;
}

__global__ void finalize(const float* __restrict__ acc, float* __restrict__ out) {
  out[0] = acc[0] / acc[1];
}

extern "C" void kernel_launch(void* const* d_in, const int* in_sizes, int n_in,
                              void* d_out, int out_size, void* d_ws, size_t ws_size,
                              hipStream_t stream) {
  const float* scores = (const float*)d_in[0];
  const int* mask = (const int*)d_in[1];
  const int* target = (const int*)d_in[2];
  float* out = (float*)d_out;
  float* acc = (float*)d_ws;

  const int Bn = in_sizes[0] / (LL * LL);
  const size_t lds_bytes = (size_t)(TC_SZ + TI_SZ) * sizeof(float);  // 152256 B

  (void)hipFuncSetAttribute((const void*)crf_inside,
                            hipFuncAttributeMaxDynamicSharedMemorySize,
                            (int)lds_bytes);

  zero_acc<<<1, 1, 0, stream>>>(acc);
  crf_inside<<<Bn, NT, lds_bytes, stream>>>(scores, mask, target, acc);
  finalize<<<1, 1, 0, stream>>>(acc, out);
}